// Round 1
// baseline (290.447 us; speedup 1.0000x reference)
//
#include <hip/hip_runtime.h>
#include <stdint.h>

// Encoder: out[n][0] = x[n]; out[n][1+i] = square(2*pi * x[n] * 2^i), i=0..14.
//
// Bit-exact replication of the f32 JAX reference:
//   t = RN32(f32(2pi) * x)          (weak-scalar promotion -> f32 multiply)
//   p = t * 2^i                     (exact: power-of-2 scaling)
//   sq = fmodf(p, f32(2pi)) < f32(pi) ? +1 : -1   (jnp.mod == fmod for +ve)
//
// Exact integer reformulation: f32(2pi) = M * 2^-21, f32(pi) = M * 2^-22
// (same 24-bit mantissa M = 13176795 = 0xC90FDB). With t = mant * 2^(E-23):
//   fmod(t*2^i, 2pif) < pif  <=>  floor(t*2^i / pif) even
//                            <=>  bit (E-1+i) of binary expansion of mant/M == 0
// q = floor(mant * 2^15 / M) holds bits 0..15 of mant/M exactly (computed via
// magic multiply: ceil(2^64/M); error < 2^-24 < 1/M => floor exact for n<2^40).
// Shift >= 17 means the bit index is negative => p < pif => fmod = p => +1.

__global__ __launch_bounds__(256) void encoder_kernel(
    const float* __restrict__ x, float* __restrict__ out, int nthreads)
{
    int t = blockIdx.x * 256 + threadIdx.x;
    if (t >= nthreads) return;
    int n = t >> 2;        // row
    int qpart = t & 3;     // which float4 of the 16-float row

    float xv = x[n];
    // f32(2*pi) = 0x40C90FDB; literal rounds to it.
    float tv = 6.28318530717958647692f * xv;

    uint32_t bits = __float_as_uint(tv);
    int E = (int)(bits >> 23) - 127;
    uint32_t mant = (bits & 0x7FFFFFu) | 0x800000u;

    constexpr uint32_t M = 13176795u;                       // mantissa of f32(2pi)
    constexpr uint64_t G = 0xFFFFFFFFFFFFFFFFull / M + 1ull; // ceil(2^64/M)
    // q = floor(mant * 2^15 / M), fits in 17 bits; exact (see header comment).
    uint64_t q = __umul64hi(((uint64_t)mant) << 15, G);

    int base = 16 - E;     // shift for i=0: bit index j = E-1+i, bit j at q>>(15-j)

    float vals[4];
    int c0 = qpart << 2;
    #pragma unroll
    for (int k = 0; k < 4; ++k) {
        int c = c0 + k;
        float v;
        if (c == 0) {
            v = xv;                       // pass-through column
        } else {
            int s = base - (c - 1);       // c-1 = i
            // s in [0,63]: real bit; s >= 64 or (tiny x) large s: bit = 0 -> +1.
            uint32_t bit = (s >= 0 && s < 64) ? (uint32_t)((q >> s) & 1ull) : 0u;
            v = bit ? -1.0f : 1.0f;
        }
        vals[k] = v;
    }
    float4 res;
    res.x = vals[0]; res.y = vals[1]; res.z = vals[2]; res.w = vals[3];
    reinterpret_cast<float4*>(out)[t] = res;   // fully coalesced 16B/lane stores
}

extern "C" void kernel_launch(void* const* d_in, const int* in_sizes, int n_in,
                              void* d_out, int out_size, void* d_ws, size_t ws_size,
                              hipStream_t stream) {
    const float* x = (const float*)d_in[0];
    float* out = (float*)d_out;
    int nrows = in_sizes[0];          // 4194304
    int nthreads = nrows * 4;         // one float4 (4 of 16 cols) per thread
    int blocks = (nthreads + 255) / 256;
    encoder_kernel<<<blocks, 256, 0, stream>>>(x, out, nthreads);
}

// Round 3
// 277.486 us; speedup vs baseline: 1.0467x; 1.0467x over previous
//
#include <hip/hip_runtime.h>
#include <stdint.h>

// Encoder: out[n][0] = x[n]; out[n][1+i] = square(2*pi * x[n] * 2^i), i=0..14.
//
// Bit-exact replication of the f32 JAX reference:
//   t = RN32(f32(2pi) * x); p = t * 2^i (exact pow2 scale);
//   sq = fmodf(p, f32(2pi)) < f32(pi) ? +1 : -1.
// f32(2pi) = M*2^-21, f32(pi) = M*2^-22, M = 13176795 (same mantissa). With
// t = mant*2^(E-23):  fmod(t*2^i, 2pif) < pif  <=>  floor(t*2^i/pif) even
//   <=>  bit (E-1+i) of the binary expansion of mant/M is 0.
// q = floor(mant*2^15 / M) (exact via magic multiply: err < 2^-24 < 1/M) holds
// those bits; q < 2^16, so clamping the shift to 31 correctly yields bit=0 for
// any out-of-range index (covers x=0 / tiny x where E is very negative).
//
// Perf shape: pure streaming-store kernel (256 MB out, 16 MB in). Round-1
// version (1 store/thread, 64K one-shot blocks) ran ~2.4 TB/s — no per-thread
// MLP. This version: 8192 blocks x 256 threads, 8 quarter-rows per thread,
// fully unrolled => 8 independent load->store chains in flight per thread;
// nontemporal stores (via clang ext_vector type — HIP float4 is rejected by
// __builtin_nontemporal_store) for the write-only stream.

typedef float v4f __attribute__((ext_vector_type(4)));

constexpr int ITER = 8;

__global__ __launch_bounds__(256) void encoder_kernel(
    const float* __restrict__ x, float* __restrict__ out, int nquarters)
{
    const int T = gridDim.x * 256;              // total threads
    const int t0 = blockIdx.x * 256 + threadIdx.x;

    constexpr uint32_t M = 13176795u;                        // mantissa of f32(2pi)
    constexpr uint64_t G = 0xFFFFFFFFFFFFFFFFull / M + 1ull; // ceil(2^64/M)

    #pragma unroll
    for (int j = 0; j < ITER; ++j) {
        int idx = t0 + j * T;                   // quarter-row index
        if (idx >= nquarters) continue;
        int n = idx >> 2;                       // row
        int qpart = idx & 3;                    // which float4 of the 16-col row

        float xv = x[n];
        float tv = 6.28318530717958647692f * xv;   // 0x40C90FDB * xv, RN

        uint32_t bits = __float_as_uint(tv);
        int E = (int)(bits >> 23) - 127;
        uint32_t mant = (bits & 0x7FFFFFu) | 0x800000u;

        uint32_t q = (uint32_t)__umul64hi(((uint64_t)mant) << 15, G);
        int base = 16 - E;                      // bit for col c: s = base-(c-1)

        int c0 = qpart << 2;
        v4f res;
        #pragma unroll
        for (int k = 0; k < 4; ++k) {
            int c = c0 + k;
            float v;
            if (c == 0) {
                v = xv;                         // pass-through column
            } else {
                uint32_t s = (uint32_t)(base - (c - 1));
                s = s > 31u ? 31u : s;          // q < 2^16: high bits 0, clamp safe
                uint32_t bit = (q >> s) & 1u;
                v = __uint_as_float(0x3F800000u | (bit << 31)); // ±1.0f
            }
            res[k] = v;
        }
        __builtin_nontemporal_store(res, reinterpret_cast<v4f*>(out) + idx);
    }
}

extern "C" void kernel_launch(void* const* d_in, const int* in_sizes, int n_in,
                              void* d_out, int out_size, void* d_ws, size_t ws_size,
                              hipStream_t stream) {
    const float* x = (const float*)d_in[0];
    float* out = (float*)d_out;
    int nrows = in_sizes[0];                    // 4194304
    int nquarters = nrows * 4;                  // 16,777,216 float4 stores
    int threads_needed = (nquarters + ITER - 1) / ITER;
    int blocks = (threads_needed + 255) / 256;  // 8192 for the bench shape
    encoder_kernel<<<blocks, 256, 0, stream>>>(x, out, nquarters);
}